// Round 21
// baseline (55.670 us; speedup 1.0000x reference)
//
#include <hip/hip_runtime.h>
#include <math.h>

// Problem constants (match reference)
constexpr int Bn = 4, Cn = 12, Hn = 256, Wn = 256;
constexpr int HWn  = Hn * Wn;        // 65536
constexpr int NPIX = Bn * HWn;       // 262144
constexpr int NPLANE = Bn * Cn;      // 48 (b,c) planes
constexpr int NMASK = 2 * NPLANE;    // 96 masks (48 pred + 48 target)
constexpr int NJOB  = 2 * NMASK;     // 192 EDT jobs (edt(mask), edt(~mask))
constexpr float LARGEf = 1.0e6f;

// fgflags layout: [0..3] = pred fg bitmask per batch (bit c), [4..7] = tgt fg
// colmask layout: [jb][8 u32]; word k bit jl = column 32k+jl EMPTY

// ---------------------------------------------------------------------------
// Kernel A: per-pixel softmax -> bit-packed masks word (bits 0..11 pred>0.5,
// bits 12..23 target one-hot), err = (prob-onehot)^2 per channel, CE partial
// per wave, per-wave OR word plain-stored (no contended atomics).
// ---------------------------------------------------------------------------
__global__ void masks_kernel(const float* __restrict__ pred,
                             const int* __restrict__ target,
                             unsigned int* __restrict__ maskw,
                             float* __restrict__ err,
                             unsigned int* __restrict__ blockOr,
                             double* __restrict__ cepart) {
    int pix = blockIdx.x * blockDim.x + threadIdx.x;   // grid = NPIX exactly
    int b = pix >> 16;            // / HW (each block lies within one b)
    int p = pix & (HWn - 1);
    float v[Cn];
    float mx = -3.4e38f;
#pragma unroll
    for (int c = 0; c < Cn; ++c) {
        v[c] = pred[(size_t)(b * Cn + c) * HWn + p];
        mx = fmaxf(mx, v[c]);
    }
    int t = target[pix];
    float raw_t = 0.f, s = 0.f;
#pragma unroll
    for (int c = 0; c < Cn; ++c) {
        if (c == t) raw_t = v[c];
        v[c] = expf(v[c] - mx);
        s += v[c];
    }
    unsigned word = 1u << (Cn + t);   // target one-hot bit
#pragma unroll
    for (int c = 0; c < Cn; ++c) {
        float prob = v[c] / s;
        int pb = (prob > 0.5f) ? 1 : 0;
        word |= (unsigned)pb << c;
        float oh = (c == t) ? 1.0f : 0.0f;
        float d = prob - oh;
        err[(size_t)(b * Cn + c) * HWn + p] = d * d;
    }
    maskw[pix] = word;
    float logp_t = raw_t - mx - logf(s);

    // wave-level OR + CE sum (no barriers), one plain store per wave
    unsigned worw = word;
    for (int o = 32; o > 0; o >>= 1) worw |= __shfl_down(worw, o, 64);
    double ced = (double)logp_t;
    for (int o = 32; o > 0; o >>= 1) ced += __shfl_down(ced, o, 64);
    int lane = threadIdx.x & 63, wv = threadIdx.x >> 6;
    if (lane == 0) {
        blockOr[blockIdx.x * 4 + wv] = worw;   // plain store, zero contention
        cepart[blockIdx.x * 4 + wv] = ced;
    }
}

__device__ __forceinline__ int mask_has_fg(const unsigned int* fgflags, int m) {
    int mm = (m < NPLANE) ? m : m - NPLANE;
    int b = mm / Cn, c = mm % Cn;
    unsigned fg = (m < NPLANE) ? fgflags[b] : fgflags[4 + b];
    return (fg >> c) & 1;
}

// ---------------------------------------------------------------------------
// Kernel C (v4): fused-polarity segmented column pass, 8 segments x 32-col
// groups (769 blocks, 3/CU resident, 32-step chains). u8 output + per-column
// empty masks. Block NMASK*8 does the fgflags reduction. (Validated R19.)
// ---------------------------------------------------------------------------
constexpr int SEG  = 8;
constexpr int SEGR = Hn / SEG;   // 32
constexpr int NCG  = 8;          // column groups of 32
constexpr int STRb = 36;         // LDS byte stride per thread (9 words, coprime 32)

__global__ void colpass_kernel(const unsigned int* __restrict__ maskw,
                               const unsigned int* __restrict__ blockOr,
                               unsigned char* __restrict__ gcol,
                               unsigned int* __restrict__ colmask,
                               unsigned int* __restrict__ fgflags) {
    int blk = blockIdx.x;         // 0..768
    int tid = threadIdx.x;
    if (blk == NMASK * NCG) {
        int lane = tid & 63, wv = tid >> 6;
        unsigned acc = 0;
#pragma unroll
        for (int k = 0; k < 16; ++k) acc |= blockOr[wv * 1024 + k * 64 + lane];
        for (int o = 32; o > 0; o >>= 1) acc |= __shfl_down(acc, o, 64);
        if (lane == 0) {
            fgflags[wv] = acc & 0xFFFu;
            fgflags[4 + wv] = acc >> Cn;
        }
        return;
    }
    int m  = blk >> 3;            // mask plane 0..95
    int cg = blk & 7;             // column group (32 cols)
    int mm = (m < NPLANE) ? m : m - NPLANE;
    int b = mm / Cn, c = mm % Cn;
    unsigned bit = (m < NPLANE) ? (unsigned)c : (unsigned)(Cn + c);
    int s  = tid >> 5;            // segment 0..7
    int jl = tid & 31;
    int j  = cg * 32 + jl;
    int r0 = s * SEGR;
    const unsigned int* mp = maskw + (size_t)b * HWn;
    unsigned char* gpA = gcol + (size_t)m * HWn;              // edt(mask)
    unsigned char* gpB = gcol + (size_t)(m + NMASK) * HWn;    // edt(~mask)

    __shared__ unsigned char ldsFA[256 * STRb];
    __shared__ unsigned char ldsFB[256 * STRb];
    __shared__ float eFA[256], eFB[256], eBA[256], eBB[256];
    __shared__ unsigned char segEmptyA[256], segEmptyB[256];

    // fwd scans (both polarities, interleaved chains); collect mask bits
    unsigned vbits = 0u;          // bit i = mask bit at row r0+i
    float cdA = LARGEf, cdB = LARGEf;
    for (int i = 0; i < SEGR; ++i) {
        unsigned w = mp[(r0 + i) * Wn + j];
        unsigned f = (w >> bit) & 1u;          // mask bit
        vbits |= f << i;
        cdA = (!f) ? 0.f : fminf(cdA + 1.f, LARGEf);   // feature A = !mask
        cdB = f ? 0.f : fminf(cdB + 1.f, LARGEf);      // feature B = mask
        ldsFA[tid * STRb + i] = (unsigned char)fminf(cdA, 255.f);
        ldsFB[tid * STRb + i] = (unsigned char)fminf(cdB, 255.f);
    }
    unsigned aBits = ~vbits;      // feature A bits (32 rows)
    eFA[tid] = cdA;
    eFB[tid] = cdB;
    eBA[tid] = aBits ? (float)__builtin_ctz(aBits) : LARGEf;
    eBB[tid] = vbits ? (float)__builtin_ctz(vbits) : LARGEf;
    segEmptyA[tid] = (aBits == 0u) ? 1 : 0;   // no A-feature in this segment
    segEmptyB[tid] = (vbits == 0u) ? 1 : 0;
    __syncthreads();
    // per-column empty masks: lanes 0..31 of wave 0 active -> ballot low bits
    if (tid < 32) {
        int emA = 1, emB = 1;
#pragma unroll
        for (int k = 0; k < SEG; ++k) {
            emA &= segEmptyA[k * 32 + tid];
            emB &= segEmptyB[k * 32 + tid];
        }
        unsigned ba = (unsigned)(__ballot(emA) & 0xFFFFFFFFull);
        unsigned bb = (unsigned)(__ballot(emB) & 0xFFFFFFFFull);
        if (tid == 0) {
            colmask[m * 8 + cg] = ba;
            colmask[(m + NMASK) * 8 + cg] = bb;
        }
    }
    // inflows
    float xA = LARGEf, xB = LARGEf;            // fwd inflow from earlier segs
    for (int sp = 0; sp < s; ++sp) {
        xA = fminf(eFA[sp * 32 + jl], fminf(xA + (float)SEGR, LARGEf));
        xB = fminf(eFB[sp * 32 + jl], fminf(xB + (float)SEGR, LARGEf));
    }
    float yA = LARGEf, yB = LARGEf;            // bwd inflow from later segs
    for (int sp = SEG - 1; sp > s; --sp) {
        yA = fminf(eBA[sp * 32 + jl], fminf(yA + (float)SEGR, LARGEf));
        yB = fminf(eBB[sp * 32 + jl], fminf(yB + (float)SEGR, LARGEf));
    }
    // output loop, backward: bwd locals as register chains (exact recurrence)
    float cA = LARGEf, cB = LARGEf;
    for (int i = SEGR - 1; i >= 0; --i) {
        unsigned f = (vbits >> i) & 1u;
        cA = (!f) ? 0.f : fminf(cA + 1.f, LARGEf);
        cB = f ? 0.f : fminf(cB + 1.f, LARGEf);
        unsigned char ufA = ldsFA[tid * STRb + i];
        unsigned char ufB = ldsFB[tid * STRb + i];
        float lfA = (ufA == 255u) ? LARGEf : (float)ufA;
        float lfB = (ufB == 255u) ? LARGEf : (float)ufB;
        float fA = fminf(lfA, fminf(xA + (float)(i + 1), LARGEf));
        float wA = fminf(cA,  fminf(yA + (float)(SEGR - i), LARGEf));
        float gA = fminf(fA, wA);
        float fB = fminf(lfB, fminf(xB + (float)(i + 1), LARGEf));
        float wB = fminf(cB,  fminf(yB + (float)(SEGR - i), LARGEf));
        float gB = fminf(fB, wB);
        // finite values <= 255 exact in u8; empty columns overridden by colmask
        gpA[(r0 + i) * Wn + j] = (unsigned char)fminf(gA, 255.f);
        gpB[(r0 + i) * Wn + j] = (unsigned char)fminf(gB, 255.f);
    }
}

// ---------------------------------------------------------------------------
// Kernel D (v8): wave handles TWO consecutive rows (both polarities) in one
// 9-segment shared-pad LDS array [pad|r0A|pad|r0B|pad|r1A|pad|r1B|pad]:
// interior X-pads are shared between neighboring data rows (scan range +-63
// blocks: data d at blocks [(2d+1)*64,(2d+2)*64) reads [1,574] within 576).
// Halves wave count (fixed stage/barrier/addressing cost amortized over 2
// rows); colmask nibbles are row-independent -> computed once. Scans are the
// validated scan4c (R20, absmax 0.0) run 4x; candidates byte-identical.
// ---------------------------------------------------------------------------
constexpr int NROWBLK = NMASK * Hn;   // 24576 row-jobs
constexpr int RPB = 4;                // waves per block; 2 rows each -> 8 rows

__device__ __forceinline__ void scan4c(const float4* __restrict__ r4,
                                       int q0, float m[4]) {
    // own block t=0: col c, elem i, d = c-i
    float4 v = r4[q0];
    m[0] = fminf(fminf(v.x, v.y + 1.f), fminf(v.z + 4.f, v.w + 9.f));
    m[1] = fminf(fminf(v.y, v.x + 1.f), fminf(v.z + 1.f, v.w + 4.f));
    m[2] = fminf(fminf(v.z, v.y + 1.f), fminf(v.w + 1.f, v.x + 4.f));
    m[3] = fminf(fminf(v.w, v.z + 1.f), fminf(v.y + 4.f, v.x + 9.f));
    for (int t = 1; t < 64; ++t) {
        float dmin = (float)(4 * t - 3);
        float mmax = fmaxf(fmaxf(m[0], m[1]), fmaxf(m[2], m[3]));
        if (dmin * dmin >= mmax) break;
        float d2[7];                      // |d| = 4t-3 .. 4t+3 (shared L/R)
#pragma unroll
        for (int k = 0; k < 7; ++k) {
            float dd = (float)(4 * t - 3 + k);
            d2[k] = dd * dd;
        }
        float4 vl = r4[q0 - t];
        float4 vr = r4[q0 + t];
        // left elem i: d = 4t + c - i -> idx (c-i)+3; right: d = 4t + i - c
#pragma unroll
        for (int c = 0; c < 4; ++c) {
            float l01 = fminf(vl.x + d2[c + 3], vl.y + d2[c + 2]);
            float l23 = fminf(vl.z + d2[c + 1], vl.w + d2[c + 0]);
            float r01 = fminf(vr.x + d2[3 - c], vr.y + d2[4 - c]);
            float r23 = fminf(vr.z + d2[5 - c], vr.w + d2[6 - c]);
            m[c] = fminf(m[c], fminf(fminf(l01, l23), fminf(r01, r23)));
        }
    }
}

__device__ __forceinline__ float4 decode4(unsigned u4, unsigned nib, float X) {
    unsigned g0 = u4 & 0xFFu, g1 = (u4 >> 8) & 0xFFu;
    unsigned g2 = (u4 >> 16) & 0xFFu, g3 = u4 >> 24;
    float4 f;
    f.x = (nib & 1u) ? X : (float)(g0 * g0);
    f.y = (nib & 2u) ? X : (float)(g1 * g1);
    f.z = (nib & 4u) ? X : (float)(g2 * g2);
    f.w = (nib & 8u) ? X : (float)(g3 * g3);
    return f;
}

__global__ void rowpass_kernel(const unsigned char* __restrict__ gcol,
                               const unsigned int* __restrict__ colmask,
                               const float* __restrict__ err,
                               const unsigned int* __restrict__ fgflags,
                               double* __restrict__ partials) {
    int blk = blockIdx.x;                 // 0..3071 (8 rows per block)
    int tid = threadIdx.x;
    int lane = tid & 63, w = tid >> 6;
    int m = (blk * 8) >> 8;               // plane (8 rows never straddle planes)
    if (!mask_has_fg(fgflags, m)) {
        if (tid < 8) partials[blk * 8 + tid] = 0.0;
        return;                           // uniform exit (no barrier divergence)
    }
    int job0 = blk * 8 + w * 2;           // this wave's first row-job
    int i0 = job0 & (Hn - 1);             // rows i0, i0+1
    const float X = 1e12f;                // == fl(1e6f*1e6f)
    __shared__ __attribute__((aligned(16))) float lds[RPB][9 * 256];  // 36 KB
    float* arr = lds[w];
    float4* a4 = (float4*)arr;            // 576 blocks: data at regions 1,3,5,7

    // colmask nibbles (row-independent within the plane)
    unsigned nibA = (colmask[m * 8 + (lane >> 3)] >> ((lane & 7) * 4)) & 0xFu;
    unsigned nibB = (colmask[(m + NMASK) * 8 + (lane >> 3)] >> ((lane & 7) * 4)) & 0xFu;

    // err prefetch for both rows (owned cols 4l..4l+3)
    int ep = (m < NPLANE) ? m : m - NPLANE;
    const float* epr = err + (size_t)ep * HWn + i0 * Wn;
    float4 ev0 = ((const float4*)epr)[lane];
    float4 ev1 = ((const float4*)(epr + Wn))[lane];

    // gcol loads: 2 rows x 2 polarities
    const unsigned char* rp = gcol + (size_t)m * HWn + i0 * Wn;            // edt(mask)
    const unsigned char* rq = gcol + (size_t)(m + NMASK) * HWn + i0 * Wn;  // edt(~mask)
    unsigned uA0 = ((const unsigned*)rp)[lane];
    unsigned uB0 = ((const unsigned*)rq)[lane];
    unsigned uA1 = ((const unsigned*)(rp + Wn))[lane];
    unsigned uB1 = ((const unsigned*)(rq + Wn))[lane];
    float4 fA0 = decode4(uA0, nibA, X);
    float4 fB0 = decode4(uB0, nibB, X);
    float4 fA1 = decode4(uA1, nibA, X);
    float4 fB1 = decode4(uB1, nibB, X);

    // stage: 5 shared pads + 4 data rows (block units; region r at r*64)
    float4 xv = make_float4(X, X, X, X);
    a4[0 * 64 + lane] = xv;
    a4[2 * 64 + lane] = xv;
    a4[4 * 64 + lane] = xv;
    a4[6 * 64 + lane] = xv;
    a4[8 * 64 + lane] = xv;
    a4[1 * 64 + lane] = fA0;
    a4[3 * 64 + lane] = fB0;
    a4[5 * 64 + lane] = fA1;
    a4[7 * 64 + lane] = fB1;
    __syncthreads();                      // uniform arrival (stage is data-indep)

    float mA0[4], mB0[4], mA1[4], mB1[4];
    scan4c(a4, 1 * 64 + lane, mA0);
    scan4c(a4, 3 * 64 + lane, mB0);
    scan4c(a4, 5 * 64 + lane, mA1);
    scan4c(a4, 7 * 64 + lane, mB1);

    // loss per row: field = sqrt(mA)+sqrt(mB); dot with err float4
    float e0v[4] = {ev0.x, ev0.y, ev0.z, ev0.w};
    float e1v[4] = {ev1.x, ev1.y, ev1.z, ev1.w};
    double v0 = 0.0, v1 = 0.0;
#pragma unroll
    for (int c = 0; c < 4; ++c) {
        float f0 = sqrtf(mA0[c]) + sqrtf(mB0[c]);
        v0 += (double)(e0v[c] * (f0 * f0));
        float f1 = sqrtf(mA1[c]) + sqrtf(mB1[c]);
        v1 += (double)(e1v[c] * (f1 * f1));
    }
    for (int o = 32; o > 0; o >>= 1) {
        v0 += __shfl_down(v0, o, 64);
        v1 += __shfl_down(v1, o, 64);
    }
    if (lane == 0) {
        partials[job0] = v0;
        partials[job0 + 1] = v1;
    }
}

// ---------------------------------------------------------------------------
// Kernel F (v2): final reduction -> scalar. double2 loads + independent
// accumulators; fixed assignment -> deterministic.
// ---------------------------------------------------------------------------
__global__ void final_kernel(const double* __restrict__ partials,
                             const double* __restrict__ cepart,
                             float* __restrict__ out) {
    int tid = threadIdx.x;
    const double2* p2 = (const double2*)partials;   // NROWBLK/2 = 12288
    const double2* c2 = (const double2*)cepart;     // 2048
    double a0 = 0.0, a1 = 0.0, a2 = 0.0, a3 = 0.0, ce0 = 0.0, ce1 = 0.0;
    for (int idx = tid; idx < NROWBLK / 2; idx += 2048) {
        double2 v = p2[idx];
        a0 += v.x; a1 += v.y;
    }
    for (int idx = tid + 1024; idx < NROWBLK / 2; idx += 2048) {
        double2 v = p2[idx];
        a2 += v.x; a3 += v.y;
    }
    for (int idx = tid; idx < 2048; idx += 1024) {
        double2 v = c2[idx];
        ce0 += v.x; ce1 += v.y;
    }
    __shared__ double sa[1024], sc[1024];
    sa[tid] = (a0 + a1) + (a2 + a3);
    sc[tid] = ce0 + ce1;
    __syncthreads();
    for (int s = 512; s > 0; s >>= 1) {
        if (tid < s) { sa[tid] += sa[tid + s]; sc[tid] += sc[tid + s]; }
        __syncthreads();
    }
    if (tid == 0) {
        double loss_sum = sa[0] / (double)NPIX;        // sum_c mean_{b,h,w}
        double cem = -sc[0] / (double)NPIX;            // ce
        double res = loss_sum / (double)Cn / (double)Bn / 3.0 + cem;
        out[0] = (float)res;
    }
}

// ---------------------------------------------------------------------------
extern "C" void kernel_launch(void* const* d_in, const int* in_sizes, int n_in,
                              void* d_out, int out_size, void* d_ws, size_t ws_size,
                              hipStream_t stream) {
    const float* pred  = (const float*)d_in[0];
    const int* target  = (const int*)d_in[1];
    float* out = (float*)d_out;
    char* ws = (char*)d_ws;

    // workspace layout (~27 MB total)
    unsigned int* maskw = (unsigned int*)ws;                         // 1 MB
    size_t off = (size_t)NPIX * 4;
    float* err = (float*)(ws + off);                                 // 12.6 MB
    off += (size_t)NPLANE * HWn * 4;
    unsigned char* gcol = (unsigned char*)(ws + off);                // 12.6 MB (u8)
    off += (size_t)NJOB * HWn;
    unsigned int* colmask = (unsigned int*)(ws + off);               // 192*8 u32 = 6 KB
    off += (size_t)NJOB * 8 * 4;
    unsigned int* fgflags = (unsigned int*)(ws + off);               // 8 u32 (pad 512)
    off += 512;
    unsigned int* blockOr = (unsigned int*)(ws + off);               // 4096*4
    off += 4096 * 4;
    double* partials = (double*)(ws + off);                          // 24576*8
    off += (size_t)NROWBLK * 8;
    double* cepart = (double*)(ws + off);                            // 4096*8

    masks_kernel<<<NPIX / 256, 256, 0, stream>>>(pred, target, maskw, err,
                                                 blockOr, cepart);
    colpass_kernel<<<NMASK * NCG + 1, 256, 0, stream>>>(maskw, blockOr, gcol,
                                                        colmask, fgflags);
    rowpass_kernel<<<NROWBLK / 8, 256, 0, stream>>>(gcol, colmask, err,
                                                    fgflags, partials);
    final_kernel<<<1, 1024, 0, stream>>>(partials, cepart, out);
}

// Round 22
// 55.538 us; speedup vs baseline: 1.0024x; 1.0024x over previous
//
#include <hip/hip_runtime.h>
#include <math.h>

// Problem constants (match reference)
constexpr int Bn = 4, Cn = 12, Hn = 256, Wn = 256;
constexpr int HWn  = Hn * Wn;        // 65536
constexpr int NPIX = Bn * HWn;       // 262144
constexpr int NPLANE = Bn * Cn;      // 48 (b,c) planes
constexpr int NMASK = 2 * NPLANE;    // 96 masks (48 pred + 48 target)
constexpr int NJOB  = 2 * NMASK;     // 192 EDT jobs (edt(mask), edt(~mask))
constexpr float LARGEf = 1.0e6f;

// fgflags layout: [0..3] = pred fg bitmask per batch (bit c), [4..7] = tgt fg
// colmask layout: [jb][8 u32]; word k bit jl = column 32k+jl EMPTY

// ---------------------------------------------------------------------------
// Kernel A: per-pixel softmax -> bit-packed masks word (bits 0..11 pred>0.5,
// bits 12..23 target one-hot), err = (prob-onehot)^2 per channel, CE partial
// per wave, per-wave OR word plain-stored (no contended atomics).
// ---------------------------------------------------------------------------
__global__ void masks_kernel(const float* __restrict__ pred,
                             const int* __restrict__ target,
                             unsigned int* __restrict__ maskw,
                             float* __restrict__ err,
                             unsigned int* __restrict__ blockOr,
                             double* __restrict__ cepart) {
    int pix = blockIdx.x * blockDim.x + threadIdx.x;   // grid = NPIX exactly
    int b = pix >> 16;            // / HW (each block lies within one b)
    int p = pix & (HWn - 1);
    float v[Cn];
    float mx = -3.4e38f;
#pragma unroll
    for (int c = 0; c < Cn; ++c) {
        v[c] = pred[(size_t)(b * Cn + c) * HWn + p];
        mx = fmaxf(mx, v[c]);
    }
    int t = target[pix];
    float raw_t = 0.f, s = 0.f;
#pragma unroll
    for (int c = 0; c < Cn; ++c) {
        if (c == t) raw_t = v[c];
        v[c] = expf(v[c] - mx);
        s += v[c];
    }
    unsigned word = 1u << (Cn + t);   // target one-hot bit
#pragma unroll
    for (int c = 0; c < Cn; ++c) {
        float prob = v[c] / s;
        int pb = (prob > 0.5f) ? 1 : 0;
        word |= (unsigned)pb << c;
        float oh = (c == t) ? 1.0f : 0.0f;
        float d = prob - oh;
        err[(size_t)(b * Cn + c) * HWn + p] = d * d;
    }
    maskw[pix] = word;
    float logp_t = raw_t - mx - logf(s);

    // wave-level OR + CE sum (no barriers), one plain store per wave
    unsigned worw = word;
    for (int o = 32; o > 0; o >>= 1) worw |= __shfl_down(worw, o, 64);
    double ced = (double)logp_t;
    for (int o = 32; o > 0; o >>= 1) ced += __shfl_down(ced, o, 64);
    int lane = threadIdx.x & 63, wv = threadIdx.x >> 6;
    if (lane == 0) {
        blockOr[blockIdx.x * 4 + wv] = worw;   // plain store, zero contention
        cepart[blockIdx.x * 4 + wv] = ced;
    }
}

__device__ __forceinline__ int mask_has_fg(const unsigned int* fgflags, int m) {
    int mm = (m < NPLANE) ? m : m - NPLANE;
    int b = mm / Cn, c = mm % Cn;
    unsigned fg = (m < NPLANE) ? fgflags[b] : fgflags[4 + b];
    return (fg >> c) & 1;
}

// ---------------------------------------------------------------------------
// Kernel C (v4): fused-polarity segmented column pass, 8 segments x 32-col
// groups (769 blocks, 3/CU resident, 32-step chains). u8 output + per-column
// empty masks. Block NMASK*8 does the fgflags reduction. (Validated R19.)
// ---------------------------------------------------------------------------
constexpr int SEG  = 8;
constexpr int SEGR = Hn / SEG;   // 32
constexpr int NCG  = 8;          // column groups of 32
constexpr int STRb = 36;         // LDS byte stride per thread (9 words, coprime 32)

__global__ void colpass_kernel(const unsigned int* __restrict__ maskw,
                               const unsigned int* __restrict__ blockOr,
                               unsigned char* __restrict__ gcol,
                               unsigned int* __restrict__ colmask,
                               unsigned int* __restrict__ fgflags) {
    int blk = blockIdx.x;         // 0..768
    int tid = threadIdx.x;
    if (blk == NMASK * NCG) {
        int lane = tid & 63, wv = tid >> 6;
        unsigned acc = 0;
#pragma unroll
        for (int k = 0; k < 16; ++k) acc |= blockOr[wv * 1024 + k * 64 + lane];
        for (int o = 32; o > 0; o >>= 1) acc |= __shfl_down(acc, o, 64);
        if (lane == 0) {
            fgflags[wv] = acc & 0xFFFu;
            fgflags[4 + wv] = acc >> Cn;
        }
        return;
    }
    int m  = blk >> 3;            // mask plane 0..95
    int cg = blk & 7;             // column group (32 cols)
    int mm = (m < NPLANE) ? m : m - NPLANE;
    int b = mm / Cn, c = mm % Cn;
    unsigned bit = (m < NPLANE) ? (unsigned)c : (unsigned)(Cn + c);
    int s  = tid >> 5;            // segment 0..7
    int jl = tid & 31;
    int j  = cg * 32 + jl;
    int r0 = s * SEGR;
    const unsigned int* mp = maskw + (size_t)b * HWn;
    unsigned char* gpA = gcol + (size_t)m * HWn;              // edt(mask)
    unsigned char* gpB = gcol + (size_t)(m + NMASK) * HWn;    // edt(~mask)

    __shared__ unsigned char ldsFA[256 * STRb];
    __shared__ unsigned char ldsFB[256 * STRb];
    __shared__ float eFA[256], eFB[256], eBA[256], eBB[256];
    __shared__ unsigned char segEmptyA[256], segEmptyB[256];

    // fwd scans (both polarities, interleaved chains); collect mask bits
    unsigned vbits = 0u;          // bit i = mask bit at row r0+i
    float cdA = LARGEf, cdB = LARGEf;
    for (int i = 0; i < SEGR; ++i) {
        unsigned w = mp[(r0 + i) * Wn + j];
        unsigned f = (w >> bit) & 1u;          // mask bit
        vbits |= f << i;
        cdA = (!f) ? 0.f : fminf(cdA + 1.f, LARGEf);   // feature A = !mask
        cdB = f ? 0.f : fminf(cdB + 1.f, LARGEf);      // feature B = mask
        ldsFA[tid * STRb + i] = (unsigned char)fminf(cdA, 255.f);
        ldsFB[tid * STRb + i] = (unsigned char)fminf(cdB, 255.f);
    }
    unsigned aBits = ~vbits;      // feature A bits (32 rows)
    eFA[tid] = cdA;
    eFB[tid] = cdB;
    eBA[tid] = aBits ? (float)__builtin_ctz(aBits) : LARGEf;
    eBB[tid] = vbits ? (float)__builtin_ctz(vbits) : LARGEf;
    segEmptyA[tid] = (aBits == 0u) ? 1 : 0;   // no A-feature in this segment
    segEmptyB[tid] = (vbits == 0u) ? 1 : 0;
    __syncthreads();
    // per-column empty masks: lanes 0..31 of wave 0 active -> ballot low bits
    if (tid < 32) {
        int emA = 1, emB = 1;
#pragma unroll
        for (int k = 0; k < SEG; ++k) {
            emA &= segEmptyA[k * 32 + tid];
            emB &= segEmptyB[k * 32 + tid];
        }
        unsigned ba = (unsigned)(__ballot(emA) & 0xFFFFFFFFull);
        unsigned bb = (unsigned)(__ballot(emB) & 0xFFFFFFFFull);
        if (tid == 0) {
            colmask[m * 8 + cg] = ba;
            colmask[(m + NMASK) * 8 + cg] = bb;
        }
    }
    // inflows
    float xA = LARGEf, xB = LARGEf;            // fwd inflow from earlier segs
    for (int sp = 0; sp < s; ++sp) {
        xA = fminf(eFA[sp * 32 + jl], fminf(xA + (float)SEGR, LARGEf));
        xB = fminf(eFB[sp * 32 + jl], fminf(xB + (float)SEGR, LARGEf));
    }
    float yA = LARGEf, yB = LARGEf;            // bwd inflow from later segs
    for (int sp = SEG - 1; sp > s; --sp) {
        yA = fminf(eBA[sp * 32 + jl], fminf(yA + (float)SEGR, LARGEf));
        yB = fminf(eBB[sp * 32 + jl], fminf(yB + (float)SEGR, LARGEf));
    }
    // output loop, backward: bwd locals as register chains (exact recurrence)
    float cA = LARGEf, cB = LARGEf;
    for (int i = SEGR - 1; i >= 0; --i) {
        unsigned f = (vbits >> i) & 1u;
        cA = (!f) ? 0.f : fminf(cA + 1.f, LARGEf);
        cB = f ? 0.f : fminf(cB + 1.f, LARGEf);
        unsigned char ufA = ldsFA[tid * STRb + i];
        unsigned char ufB = ldsFB[tid * STRb + i];
        float lfA = (ufA == 255u) ? LARGEf : (float)ufA;
        float lfB = (ufB == 255u) ? LARGEf : (float)ufB;
        float fA = fminf(lfA, fminf(xA + (float)(i + 1), LARGEf));
        float wA = fminf(cA,  fminf(yA + (float)(SEGR - i), LARGEf));
        float gA = fminf(fA, wA);
        float fB = fminf(lfB, fminf(xB + (float)(i + 1), LARGEf));
        float wB = fminf(cB,  fminf(yB + (float)(SEGR - i), LARGEf));
        float gB = fminf(fB, wB);
        // finite values <= 255 exact in u8; empty columns overridden by colmask
        gpA[(r0 + i) * Wn + j] = (unsigned char)fminf(gA, 255.f);
        gpB[(r0 + i) * Wn + j] = (unsigned char)fminf(gB, 255.f);
    }
}

// ---------------------------------------------------------------------------
// Kernel D (v9): R20's wave-per-row consecutive-column scan (champion), with
// the block-wide __syncthreads() replaced by a WAVE-LOCAL LDS drain. Each
// wave uses a private LDS slice (lds[w]); no cross-wave reads exist, so the
// only ordering needed is this wave's own ds_writes before its ds_reads:
// s_waitcnt lgkmcnt(0) (+"memory" clobber pins the compiler's op order).
// Waves stage -> scan -> retire fully independently (no rendezvous skew).
// ---------------------------------------------------------------------------
constexpr int RPAD = 256;
constexpr int NROWBLK = NMASK * Hn;   // 24576 row-jobs
constexpr int RPB = 4;                // rows per block (one per wave)

__device__ __forceinline__ void scan4c(const float4* __restrict__ r4,
                                       int q0, float m[4]) {
    // own block t=0: col c, elem i, d = c-i
    float4 v = r4[q0];
    m[0] = fminf(fminf(v.x, v.y + 1.f), fminf(v.z + 4.f, v.w + 9.f));
    m[1] = fminf(fminf(v.y, v.x + 1.f), fminf(v.z + 1.f, v.w + 4.f));
    m[2] = fminf(fminf(v.z, v.y + 1.f), fminf(v.w + 1.f, v.x + 4.f));
    m[3] = fminf(fminf(v.w, v.z + 1.f), fminf(v.y + 4.f, v.x + 9.f));
    for (int t = 1; t < 64; ++t) {
        float dmin = (float)(4 * t - 3);
        float mmax = fmaxf(fmaxf(m[0], m[1]), fmaxf(m[2], m[3]));
        if (dmin * dmin >= mmax) break;
        float d2[7];                      // |d| = 4t-3 .. 4t+3 (shared L/R)
#pragma unroll
        for (int k = 0; k < 7; ++k) {
            float dd = (float)(4 * t - 3 + k);
            d2[k] = dd * dd;
        }
        float4 vl = r4[q0 - t];
        float4 vr = r4[q0 + t];
        // left elem i: d = 4t + c - i -> idx (c-i)+3; right: d = 4t + i - c
#pragma unroll
        for (int c = 0; c < 4; ++c) {
            float l01 = fminf(vl.x + d2[c + 3], vl.y + d2[c + 2]);
            float l23 = fminf(vl.z + d2[c + 1], vl.w + d2[c + 0]);
            float r01 = fminf(vr.x + d2[3 - c], vr.y + d2[4 - c]);
            float r23 = fminf(vr.z + d2[5 - c], vr.w + d2[6 - c]);
            m[c] = fminf(m[c], fminf(fminf(l01, l23), fminf(r01, r23)));
        }
    }
}

__global__ void rowpass_kernel(const unsigned char* __restrict__ gcol,
                               const unsigned int* __restrict__ colmask,
                               const float* __restrict__ err,
                               const unsigned int* __restrict__ fgflags,
                               double* __restrict__ partials) {
    int blk = blockIdx.x;                 // 0..6143
    int tid = threadIdx.x;
    int lane = tid & 63, w = tid >> 6;
    int m = (blk * RPB) >> 8;             // plane (uniform: 4 rows never straddle)
    if (!mask_has_fg(fgflags, m)) {
        if (tid < RPB) partials[blk * RPB + tid] = 0.0;
        return;                           // uniform exit
    }
    int job = blk * RPB + w;              // this wave's row-job
    int i = job & (Hn - 1);               // row
    const float X = 1e12f;                // == fl(1e6f*1e6f)
    __shared__ __attribute__((aligned(16))) float lds[RPB][2][Wn + 2 * RPAD];
    float* rA = lds[w][0];                // wave-private slice
    float* rB = lds[w][1];

    // prefetch err for owned cols 4l..4l+3 (one float4; consumed post-scan)
    int ep = (m < NPLANE) ? m : m - NPLANE;
    const float* epr = err + (size_t)ep * HWn + i * Wn;
    float4 ev4 = ((const float4*)epr)[lane];

    // stage: lane covers block `lane` = cols 4l..4l+3 (u8 loads + colmask)
    const unsigned char* rp = gcol + (size_t)m * HWn + i * Wn;            // edt(mask)
    const unsigned char* rq = gcol + (size_t)(m + NMASK) * HWn + i * Wn;  // edt(~mask)
    unsigned ua4 = ((const unsigned*)rp)[lane];
    unsigned ub4 = ((const unsigned*)rq)[lane];
    unsigned nibA = (colmask[m * 8 + (lane >> 3)] >> ((lane & 7) * 4)) & 0xFu;
    unsigned nibB = (colmask[(m + NMASK) * 8 + (lane >> 3)] >> ((lane & 7) * 4)) & 0xFu;
    float4 fa, fb;
    {
        unsigned g0 = ua4 & 0xFFu, g1 = (ua4 >> 8) & 0xFFu;
        unsigned g2 = (ua4 >> 16) & 0xFFu, g3 = ua4 >> 24;
        fa.x = (nibA & 1u) ? X : (float)(g0 * g0);
        fa.y = (nibA & 2u) ? X : (float)(g1 * g1);
        fa.z = (nibA & 4u) ? X : (float)(g2 * g2);
        fa.w = (nibA & 8u) ? X : (float)(g3 * g3);
        g0 = ub4 & 0xFFu; g1 = (ub4 >> 8) & 0xFFu;
        g2 = (ub4 >> 16) & 0xFFu; g3 = ub4 >> 24;
        fb.x = (nibB & 1u) ? X : (float)(g0 * g0);
        fb.y = (nibB & 2u) ? X : (float)(g1 * g1);
        fb.z = (nibB & 4u) ? X : (float)(g2 * g2);
        fb.w = (nibB & 8u) ? X : (float)(g3 * g3);
    }
    float4 xv = make_float4(X, X, X, X);
    ((float4*)rA)[lane] = xv;                       // left pad [0..255]
    ((float4*)(rA + RPAD))[lane] = fa;              // data
    ((float4*)(rA + RPAD + Wn))[lane] = xv;         // right pad
    ((float4*)rB)[lane] = xv;
    ((float4*)(rB + RPAD))[lane] = fb;
    ((float4*)(rB + RPAD + Wn))[lane] = xv;
    // wave-local drain: this wave's LDS writes complete before its reads.
    // No cross-wave LDS sharing exists -> no block barrier needed.
    asm volatile("s_waitcnt lgkmcnt(0)" ::: "memory");

    int q0 = (RPAD / 4) + lane;           // own block index in padded row
    float mA[4], mB[4];
    scan4c((const float4*)rA, q0, mA);
    scan4c((const float4*)rB, q0, mB);

    // loss: field = sqrt(mA)+sqrt(mB); dot with prefetched err float4
    float evv[4] = {ev4.x, ev4.y, ev4.z, ev4.w};
    double v = 0.0;
#pragma unroll
    for (int c = 0; c < 4; ++c) {
        float f = sqrtf(mA[c]) + sqrtf(mB[c]);
        v += (double)(evv[c] * (f * f));
    }
    for (int o = 32; o > 0; o >>= 1) v += __shfl_down(v, o, 64);
    if (lane == 0) partials[job] = v;
}

// ---------------------------------------------------------------------------
// Kernel F (v2): final reduction -> scalar. double2 loads + independent
// accumulators; fixed assignment -> deterministic.
// ---------------------------------------------------------------------------
__global__ void final_kernel(const double* __restrict__ partials,
                             const double* __restrict__ cepart,
                             float* __restrict__ out) {
    int tid = threadIdx.x;
    const double2* p2 = (const double2*)partials;   // NROWBLK/2 = 12288
    const double2* c2 = (const double2*)cepart;     // 2048
    double a0 = 0.0, a1 = 0.0, a2 = 0.0, a3 = 0.0, ce0 = 0.0, ce1 = 0.0;
    for (int idx = tid; idx < NROWBLK / 2; idx += 2048) {
        double2 v = p2[idx];
        a0 += v.x; a1 += v.y;
    }
    for (int idx = tid + 1024; idx < NROWBLK / 2; idx += 2048) {
        double2 v = p2[idx];
        a2 += v.x; a3 += v.y;
    }
    for (int idx = tid; idx < 2048; idx += 1024) {
        double2 v = c2[idx];
        ce0 += v.x; ce1 += v.y;
    }
    __shared__ double sa[1024], sc[1024];
    sa[tid] = (a0 + a1) + (a2 + a3);
    sc[tid] = ce0 + ce1;
    __syncthreads();
    for (int s = 512; s > 0; s >>= 1) {
        if (tid < s) { sa[tid] += sa[tid + s]; sc[tid] += sc[tid + s]; }
        __syncthreads();
    }
    if (tid == 0) {
        double loss_sum = sa[0] / (double)NPIX;        // sum_c mean_{b,h,w}
        double cem = -sc[0] / (double)NPIX;            // ce
        double res = loss_sum / (double)Cn / (double)Bn / 3.0 + cem;
        out[0] = (float)res;
    }
}

// ---------------------------------------------------------------------------
extern "C" void kernel_launch(void* const* d_in, const int* in_sizes, int n_in,
                              void* d_out, int out_size, void* d_ws, size_t ws_size,
                              hipStream_t stream) {
    const float* pred  = (const float*)d_in[0];
    const int* target  = (const int*)d_in[1];
    float* out = (float*)d_out;
    char* ws = (char*)d_ws;

    // workspace layout (~27 MB total)
    unsigned int* maskw = (unsigned int*)ws;                         // 1 MB
    size_t off = (size_t)NPIX * 4;
    float* err = (float*)(ws + off);                                 // 12.6 MB
    off += (size_t)NPLANE * HWn * 4;
    unsigned char* gcol = (unsigned char*)(ws + off);                // 12.6 MB (u8)
    off += (size_t)NJOB * HWn;
    unsigned int* colmask = (unsigned int*)(ws + off);               // 192*8 u32 = 6 KB
    off += (size_t)NJOB * 8 * 4;
    unsigned int* fgflags = (unsigned int*)(ws + off);               // 8 u32 (pad 512)
    off += 512;
    unsigned int* blockOr = (unsigned int*)(ws + off);               // 4096*4
    off += 4096 * 4;
    double* partials = (double*)(ws + off);                          // 24576*8
    off += (size_t)NROWBLK * 8;
    double* cepart = (double*)(ws + off);                            // 4096*8

    masks_kernel<<<NPIX / 256, 256, 0, stream>>>(pred, target, maskw, err,
                                                 blockOr, cepart);
    colpass_kernel<<<NMASK * NCG + 1, 256, 0, stream>>>(maskw, blockOr, gcol,
                                                        colmask, fgflags);
    rowpass_kernel<<<NROWBLK / RPB, 256, 0, stream>>>(gcol, colmask, err,
                                                      fgflags, partials);
    final_kernel<<<1, 1024, 0, stream>>>(partials, cepart, out);
}

// Round 23
// 54.554 us; speedup vs baseline: 1.0205x; 1.0180x over previous
//
#include <hip/hip_runtime.h>
#include <math.h>

// Problem constants (match reference)
constexpr int Bn = 4, Cn = 12, Hn = 256, Wn = 256;
constexpr int HWn  = Hn * Wn;        // 65536
constexpr int NPIX = Bn * HWn;       // 262144
constexpr int NPLANE = Bn * Cn;      // 48 (b,c) planes
constexpr int NMASK = 2 * NPLANE;    // 96 masks (48 pred + 48 target)
constexpr int NJOB  = 2 * NMASK;     // 192 EDT jobs (edt(mask), edt(~mask))
constexpr float LARGEf = 1.0e6f;

// fgflags layout: [0..3] = pred fg bitmask per batch (bit c), [4..7] = tgt fg
// colmask layout: [jb][8 u32]; word k bit jl = column 32k+jl EMPTY

// ---------------------------------------------------------------------------
// Kernel A: per-pixel softmax -> bit-packed masks word (bits 0..11 pred>0.5,
// bits 12..23 target one-hot), err = (prob-onehot)^2 per channel, CE partial
// per wave, per-wave OR word plain-stored (no contended atomics).
// ---------------------------------------------------------------------------
__global__ void masks_kernel(const float* __restrict__ pred,
                             const int* __restrict__ target,
                             unsigned int* __restrict__ maskw,
                             float* __restrict__ err,
                             unsigned int* __restrict__ blockOr,
                             double* __restrict__ cepart) {
    int pix = blockIdx.x * blockDim.x + threadIdx.x;   // grid = NPIX exactly
    int b = pix >> 16;            // / HW (each block lies within one b)
    int p = pix & (HWn - 1);
    float v[Cn];
    float mx = -3.4e38f;
#pragma unroll
    for (int c = 0; c < Cn; ++c) {
        v[c] = pred[(size_t)(b * Cn + c) * HWn + p];
        mx = fmaxf(mx, v[c]);
    }
    int t = target[pix];
    float raw_t = 0.f, s = 0.f;
#pragma unroll
    for (int c = 0; c < Cn; ++c) {
        if (c == t) raw_t = v[c];
        v[c] = expf(v[c] - mx);
        s += v[c];
    }
    unsigned word = 1u << (Cn + t);   // target one-hot bit
#pragma unroll
    for (int c = 0; c < Cn; ++c) {
        float prob = v[c] / s;
        int pb = (prob > 0.5f) ? 1 : 0;
        word |= (unsigned)pb << c;
        float oh = (c == t) ? 1.0f : 0.0f;
        float d = prob - oh;
        err[(size_t)(b * Cn + c) * HWn + p] = d * d;
    }
    maskw[pix] = word;
    float logp_t = raw_t - mx - logf(s);

    // wave-level OR + CE sum (no barriers), one plain store per wave
    unsigned worw = word;
    for (int o = 32; o > 0; o >>= 1) worw |= __shfl_down(worw, o, 64);
    double ced = (double)logp_t;
    for (int o = 32; o > 0; o >>= 1) ced += __shfl_down(ced, o, 64);
    int lane = threadIdx.x & 63, wv = threadIdx.x >> 6;
    if (lane == 0) {
        blockOr[blockIdx.x * 4 + wv] = worw;   // plain store, zero contention
        cepart[blockIdx.x * 4 + wv] = ced;
    }
}

__device__ __forceinline__ int mask_has_fg(const unsigned int* fgflags, int m) {
    int mm = (m < NPLANE) ? m : m - NPLANE;
    int b = mm / Cn, c = mm % Cn;
    unsigned fg = (m < NPLANE) ? fgflags[b] : fgflags[4 + b];
    return (fg >> c) & 1;
}

// ---------------------------------------------------------------------------
// Kernel C (v4): fused-polarity segmented column pass, 8 segments x 32-col
// groups (769 blocks, 3/CU resident, 32-step chains). u8 output + per-column
// empty masks. Block NMASK*8 does the fgflags reduction. (Validated R19.)
// ---------------------------------------------------------------------------
constexpr int SEG  = 8;
constexpr int SEGR = Hn / SEG;   // 32
constexpr int NCG  = 8;          // column groups of 32
constexpr int STRb = 36;         // LDS byte stride per thread (9 words, coprime 32)

__global__ void colpass_kernel(const unsigned int* __restrict__ maskw,
                               const unsigned int* __restrict__ blockOr,
                               unsigned char* __restrict__ gcol,
                               unsigned int* __restrict__ colmask,
                               unsigned int* __restrict__ fgflags) {
    int blk = blockIdx.x;         // 0..768
    int tid = threadIdx.x;
    if (blk == NMASK * NCG) {
        int lane = tid & 63, wv = tid >> 6;
        unsigned acc = 0;
#pragma unroll
        for (int k = 0; k < 16; ++k) acc |= blockOr[wv * 1024 + k * 64 + lane];
        for (int o = 32; o > 0; o >>= 1) acc |= __shfl_down(acc, o, 64);
        if (lane == 0) {
            fgflags[wv] = acc & 0xFFFu;
            fgflags[4 + wv] = acc >> Cn;
        }
        return;
    }
    int m  = blk >> 3;            // mask plane 0..95
    int cg = blk & 7;             // column group (32 cols)
    int mm = (m < NPLANE) ? m : m - NPLANE;
    int b = mm / Cn, c = mm % Cn;
    unsigned bit = (m < NPLANE) ? (unsigned)c : (unsigned)(Cn + c);
    int s  = tid >> 5;            // segment 0..7
    int jl = tid & 31;
    int j  = cg * 32 + jl;
    int r0 = s * SEGR;
    const unsigned int* mp = maskw + (size_t)b * HWn;
    unsigned char* gpA = gcol + (size_t)m * HWn;              // edt(mask)
    unsigned char* gpB = gcol + (size_t)(m + NMASK) * HWn;    // edt(~mask)

    __shared__ unsigned char ldsFA[256 * STRb];
    __shared__ unsigned char ldsFB[256 * STRb];
    __shared__ float eFA[256], eFB[256], eBA[256], eBB[256];
    __shared__ unsigned char segEmptyA[256], segEmptyB[256];

    // fwd scans (both polarities, interleaved chains); collect mask bits
    unsigned vbits = 0u;          // bit i = mask bit at row r0+i
    float cdA = LARGEf, cdB = LARGEf;
    for (int i = 0; i < SEGR; ++i) {
        unsigned w = mp[(r0 + i) * Wn + j];
        unsigned f = (w >> bit) & 1u;          // mask bit
        vbits |= f << i;
        cdA = (!f) ? 0.f : fminf(cdA + 1.f, LARGEf);   // feature A = !mask
        cdB = f ? 0.f : fminf(cdB + 1.f, LARGEf);      // feature B = mask
        ldsFA[tid * STRb + i] = (unsigned char)fminf(cdA, 255.f);
        ldsFB[tid * STRb + i] = (unsigned char)fminf(cdB, 255.f);
    }
    unsigned aBits = ~vbits;      // feature A bits (32 rows)
    eFA[tid] = cdA;
    eFB[tid] = cdB;
    eBA[tid] = aBits ? (float)__builtin_ctz(aBits) : LARGEf;
    eBB[tid] = vbits ? (float)__builtin_ctz(vbits) : LARGEf;
    segEmptyA[tid] = (aBits == 0u) ? 1 : 0;   // no A-feature in this segment
    segEmptyB[tid] = (vbits == 0u) ? 1 : 0;
    __syncthreads();
    // per-column empty masks: lanes 0..31 of wave 0 active -> ballot low bits
    if (tid < 32) {
        int emA = 1, emB = 1;
#pragma unroll
        for (int k = 0; k < SEG; ++k) {
            emA &= segEmptyA[k * 32 + tid];
            emB &= segEmptyB[k * 32 + tid];
        }
        unsigned ba = (unsigned)(__ballot(emA) & 0xFFFFFFFFull);
        unsigned bb = (unsigned)(__ballot(emB) & 0xFFFFFFFFull);
        if (tid == 0) {
            colmask[m * 8 + cg] = ba;
            colmask[(m + NMASK) * 8 + cg] = bb;
        }
    }
    // inflows
    float xA = LARGEf, xB = LARGEf;            // fwd inflow from earlier segs
    for (int sp = 0; sp < s; ++sp) {
        xA = fminf(eFA[sp * 32 + jl], fminf(xA + (float)SEGR, LARGEf));
        xB = fminf(eFB[sp * 32 + jl], fminf(xB + (float)SEGR, LARGEf));
    }
    float yA = LARGEf, yB = LARGEf;            // bwd inflow from later segs
    for (int sp = SEG - 1; sp > s; --sp) {
        yA = fminf(eBA[sp * 32 + jl], fminf(yA + (float)SEGR, LARGEf));
        yB = fminf(eBB[sp * 32 + jl], fminf(yB + (float)SEGR, LARGEf));
    }
    // output loop, backward: bwd locals as register chains (exact recurrence)
    float cA = LARGEf, cB = LARGEf;
    for (int i = SEGR - 1; i >= 0; --i) {
        unsigned f = (vbits >> i) & 1u;
        cA = (!f) ? 0.f : fminf(cA + 1.f, LARGEf);
        cB = f ? 0.f : fminf(cB + 1.f, LARGEf);
        unsigned char ufA = ldsFA[tid * STRb + i];
        unsigned char ufB = ldsFB[tid * STRb + i];
        float lfA = (ufA == 255u) ? LARGEf : (float)ufA;
        float lfB = (ufB == 255u) ? LARGEf : (float)ufB;
        float fA = fminf(lfA, fminf(xA + (float)(i + 1), LARGEf));
        float wA = fminf(cA,  fminf(yA + (float)(SEGR - i), LARGEf));
        float gA = fminf(fA, wA);
        float fB = fminf(lfB, fminf(xB + (float)(i + 1), LARGEf));
        float wB = fminf(cB,  fminf(yB + (float)(SEGR - i), LARGEf));
        float gB = fminf(fB, wB);
        // finite values <= 255 exact in u8; empty columns overridden by colmask
        gpA[(r0 + i) * Wn + j] = (unsigned char)fminf(gA, 255.f);
        gpB[(r0 + i) * Wn + j] = (unsigned char)fminf(gB, 255.f);
    }
}

// ---------------------------------------------------------------------------
// Kernel D (v10): R20's wave-per-row consecutive-column scan (champion) with
// SHARED-PAD per-wave LDS layout [pad|rA|pad|rB|pad] (5 x 256 blocks = 5 KB
// per wave vs 6 KB): middle pad serves as rA's right pad AND rB's left pad.
// Bounds: rA at blocks [64,128), reads q0+-63 in [1,190]; rB at [192,256),
// reads in [129,318] - all within [0,320). 20 KB/block -> 8 blocks/CU =
// 32 waves/CU (vs 24). Scan/decode/epilogue byte-identical to R20.
// ---------------------------------------------------------------------------
constexpr int NROWBLK = NMASK * Hn;   // 24576 row-jobs
constexpr int RPB = 4;                // rows per block (one per wave)

__device__ __forceinline__ void scan4c(const float4* __restrict__ r4,
                                       int q0, float m[4]) {
    // own block t=0: col c, elem i, d = c-i
    float4 v = r4[q0];
    m[0] = fminf(fminf(v.x, v.y + 1.f), fminf(v.z + 4.f, v.w + 9.f));
    m[1] = fminf(fminf(v.y, v.x + 1.f), fminf(v.z + 1.f, v.w + 4.f));
    m[2] = fminf(fminf(v.z, v.y + 1.f), fminf(v.w + 1.f, v.x + 4.f));
    m[3] = fminf(fminf(v.w, v.z + 1.f), fminf(v.y + 4.f, v.x + 9.f));
    for (int t = 1; t < 64; ++t) {
        float dmin = (float)(4 * t - 3);
        float mmax = fmaxf(fmaxf(m[0], m[1]), fmaxf(m[2], m[3]));
        if (dmin * dmin >= mmax) break;
        float d2[7];                      // |d| = 4t-3 .. 4t+3 (shared L/R)
#pragma unroll
        for (int k = 0; k < 7; ++k) {
            float dd = (float)(4 * t - 3 + k);
            d2[k] = dd * dd;
        }
        float4 vl = r4[q0 - t];
        float4 vr = r4[q0 + t];
        // left elem i: d = 4t + c - i -> idx (c-i)+3; right: d = 4t + i - c
#pragma unroll
        for (int c = 0; c < 4; ++c) {
            float l01 = fminf(vl.x + d2[c + 3], vl.y + d2[c + 2]);
            float l23 = fminf(vl.z + d2[c + 1], vl.w + d2[c + 0]);
            float r01 = fminf(vr.x + d2[3 - c], vr.y + d2[4 - c]);
            float r23 = fminf(vr.z + d2[5 - c], vr.w + d2[6 - c]);
            m[c] = fminf(m[c], fminf(fminf(l01, l23), fminf(r01, r23)));
        }
    }
}

__global__ void rowpass_kernel(const unsigned char* __restrict__ gcol,
                               const unsigned int* __restrict__ colmask,
                               const float* __restrict__ err,
                               const unsigned int* __restrict__ fgflags,
                               double* __restrict__ partials) {
    int blk = blockIdx.x;                 // 0..6143
    int tid = threadIdx.x;
    int lane = tid & 63, w = tid >> 6;
    int m = (blk * RPB) >> 8;             // plane (uniform: 4 rows never straddle)
    if (!mask_has_fg(fgflags, m)) {
        if (tid < RPB) partials[blk * RPB + tid] = 0.0;
        return;                           // uniform exit (no barrier divergence)
    }
    int job = blk * RPB + w;              // this wave's row-job
    int i = job & (Hn - 1);               // row
    const float X = 1e12f;                // == fl(1e6f*1e6f)
    // shared-pad wave slice: 5 regions x 256 floats = 1280 floats = 5 KB
    __shared__ __attribute__((aligned(16))) float lds[RPB][5 * 256];  // 20 KB
    float4* a4 = (float4*)lds[w];         // 320 float4-blocks

    // prefetch err for owned cols 4l..4l+3 (one float4; consumed post-scan)
    int ep = (m < NPLANE) ? m : m - NPLANE;
    const float* epr = err + (size_t)ep * HWn + i * Wn;
    float4 ev4 = ((const float4*)epr)[lane];

    // stage: lane covers block `lane` = cols 4l..4l+3 (u8 loads + colmask)
    const unsigned char* rp = gcol + (size_t)m * HWn + i * Wn;            // edt(mask)
    const unsigned char* rq = gcol + (size_t)(m + NMASK) * HWn + i * Wn;  // edt(~mask)
    unsigned ua4 = ((const unsigned*)rp)[lane];
    unsigned ub4 = ((const unsigned*)rq)[lane];
    unsigned nibA = (colmask[m * 8 + (lane >> 3)] >> ((lane & 7) * 4)) & 0xFu;
    unsigned nibB = (colmask[(m + NMASK) * 8 + (lane >> 3)] >> ((lane & 7) * 4)) & 0xFu;
    float4 fa, fb;
    {
        unsigned g0 = ua4 & 0xFFu, g1 = (ua4 >> 8) & 0xFFu;
        unsigned g2 = (ua4 >> 16) & 0xFFu, g3 = ua4 >> 24;
        fa.x = (nibA & 1u) ? X : (float)(g0 * g0);
        fa.y = (nibA & 2u) ? X : (float)(g1 * g1);
        fa.z = (nibA & 4u) ? X : (float)(g2 * g2);
        fa.w = (nibA & 8u) ? X : (float)(g3 * g3);
        g0 = ub4 & 0xFFu; g1 = (ub4 >> 8) & 0xFFu;
        g2 = (ub4 >> 16) & 0xFFu; g3 = ub4 >> 24;
        fb.x = (nibB & 1u) ? X : (float)(g0 * g0);
        fb.y = (nibB & 2u) ? X : (float)(g1 * g1);
        fb.z = (nibB & 4u) ? X : (float)(g2 * g2);
        fb.w = (nibB & 8u) ? X : (float)(g3 * g3);
    }
    float4 xv = make_float4(X, X, X, X);
    a4[0 * 64 + lane] = xv;               // left pad (blocks 0..63)
    a4[1 * 64 + lane] = fa;               // rA data (blocks 64..127)
    a4[2 * 64 + lane] = xv;               // middle pad (rA-right / rB-left)
    a4[3 * 64 + lane] = fb;               // rB data (blocks 192..255)
    a4[4 * 64 + lane] = xv;               // right pad (blocks 256..319)
    __syncthreads();                      // uniform arrival (stage is data-indep)

    float mA[4], mB[4];
    scan4c(a4, 1 * 64 + lane, mA);
    scan4c(a4, 3 * 64 + lane, mB);

    // loss: field = sqrt(mA)+sqrt(mB); dot with prefetched err float4
    float evv[4] = {ev4.x, ev4.y, ev4.z, ev4.w};
    double v = 0.0;
#pragma unroll
    for (int c = 0; c < 4; ++c) {
        float f = sqrtf(mA[c]) + sqrtf(mB[c]);
        v += (double)(evv[c] * (f * f));
    }
    for (int o = 32; o > 0; o >>= 1) v += __shfl_down(v, o, 64);
    if (lane == 0) partials[job] = v;
}

// ---------------------------------------------------------------------------
// Kernel F (v2): final reduction -> scalar. double2 loads + independent
// accumulators; fixed assignment -> deterministic.
// ---------------------------------------------------------------------------
__global__ void final_kernel(const double* __restrict__ partials,
                             const double* __restrict__ cepart,
                             float* __restrict__ out) {
    int tid = threadIdx.x;
    const double2* p2 = (const double2*)partials;   // NROWBLK/2 = 12288
    const double2* c2 = (const double2*)cepart;     // 2048
    double a0 = 0.0, a1 = 0.0, a2 = 0.0, a3 = 0.0, ce0 = 0.0, ce1 = 0.0;
    for (int idx = tid; idx < NROWBLK / 2; idx += 2048) {
        double2 v = p2[idx];
        a0 += v.x; a1 += v.y;
    }
    for (int idx = tid + 1024; idx < NROWBLK / 2; idx += 2048) {
        double2 v = p2[idx];
        a2 += v.x; a3 += v.y;
    }
    for (int idx = tid; idx < 2048; idx += 1024) {
        double2 v = c2[idx];
        ce0 += v.x; ce1 += v.y;
    }
    __shared__ double sa[1024], sc[1024];
    sa[tid] = (a0 + a1) + (a2 + a3);
    sc[tid] = ce0 + ce1;
    __syncthreads();
    for (int s = 512; s > 0; s >>= 1) {
        if (tid < s) { sa[tid] += sa[tid + s]; sc[tid] += sc[tid + s]; }
        __syncthreads();
    }
    if (tid == 0) {
        double loss_sum = sa[0] / (double)NPIX;        // sum_c mean_{b,h,w}
        double cem = -sc[0] / (double)NPIX;            // ce
        double res = loss_sum / (double)Cn / (double)Bn / 3.0 + cem;
        out[0] = (float)res;
    }
}

// ---------------------------------------------------------------------------
extern "C" void kernel_launch(void* const* d_in, const int* in_sizes, int n_in,
                              void* d_out, int out_size, void* d_ws, size_t ws_size,
                              hipStream_t stream) {
    const float* pred  = (const float*)d_in[0];
    const int* target  = (const int*)d_in[1];
    float* out = (float*)d_out;
    char* ws = (char*)d_ws;

    // workspace layout (~27 MB total)
    unsigned int* maskw = (unsigned int*)ws;                         // 1 MB
    size_t off = (size_t)NPIX * 4;
    float* err = (float*)(ws + off);                                 // 12.6 MB
    off += (size_t)NPLANE * HWn * 4;
    unsigned char* gcol = (unsigned char*)(ws + off);                // 12.6 MB (u8)
    off += (size_t)NJOB * HWn;
    unsigned int* colmask = (unsigned int*)(ws + off);               // 192*8 u32 = 6 KB
    off += (size_t)NJOB * 8 * 4;
    unsigned int* fgflags = (unsigned int*)(ws + off);               // 8 u32 (pad 512)
    off += 512;
    unsigned int* blockOr = (unsigned int*)(ws + off);               // 4096*4
    off += 4096 * 4;
    double* partials = (double*)(ws + off);                          // 24576*8
    off += (size_t)NROWBLK * 8;
    double* cepart = (double*)(ws + off);                            // 4096*8

    masks_kernel<<<NPIX / 256, 256, 0, stream>>>(pred, target, maskw, err,
                                                 blockOr, cepart);
    colpass_kernel<<<NMASK * NCG + 1, 256, 0, stream>>>(maskw, blockOr, gcol,
                                                        colmask, fgflags);
    rowpass_kernel<<<NROWBLK / RPB, 256, 0, stream>>>(gcol, colmask, err,
                                                      fgflags, partials);
    final_kernel<<<1, 1024, 0, stream>>>(partials, cepart, out);
}